// Round 19
// baseline (47.991 us; speedup 1.0000x reference)
//
#include <hip/hip_runtime.h>

// LocNet2d on MFMA fp16, 5 dispatches:
//   l1_mfma: R12-v3 (s2-cell block, staged once, coalesced A2 stores)
//   gemm0:   per-s GEMM M=128,N=512,K=8192, splitK=32, TILE N=128, K-step=32,
//            512 blocks x 512 thr, 48 KB LDS -> 2 blocks/CU, dbuf LDS,
//            counted vmcnt(3), global_load_lds. P2 fp16.
//   reduce2: fp16 P2 (128 slices) -> fp32 accum -> A3 fp16, coalesced.
//   gemm1:   128 blocks, N=64, splitK=16 -> P3 fp16
//   out:     reduce P3 + head.

typedef _Float16 f16;
typedef _Float16 half8 __attribute__((ext_vector_type(8)));
typedef _Float16 half4 __attribute__((ext_vector_type(4)));
typedef float f32x4 __attribute__((ext_vector_type(4)));

#define SWZ(r, c) ((((r) << 6) + (c)) ^ (((r) & 7) << 3))
#define SWZL(r, c) ((((r) << 10) + (c)) ^ (((r) & 7) << 3))

#define GLOAD_LDS16(G, L)                                                     \
  __builtin_amdgcn_global_load_lds(                                           \
      (const __attribute__((address_space(1))) void*)(G),                     \
      (__attribute__((address_space(3))) void*)(L), 16, 0, 0)

__global__ __launch_bounds__(256) void l1_mfma(const float* __restrict__ x,
                                               const float* __restrict__ w1,
                                               f16* __restrict__ A2) {
  const int o0 = blockIdx.x << 5;
  const int s2 = blockIdx.y;
  const int b0 = blockIdx.z << 5;
  const int p2 = s2 >> 1, q2 = s2 & 1;
  __shared__ __align__(16) f16 Xs[32 * 1024];  // 64 KB
  __shared__ __align__(16) f16 Ws[32 * 1024];  // 64 KB
  const int t = threadIdx.x;
#pragma unroll
  for (int i = 0; i < 8; ++i) {
    int e = (i << 8) + t;
    int row = e >> 6, rem = e & 63, g = rem >> 2, j = rem & 3;
    half4 z = {};
    *(half4*)&Xs[SWZL(row, g * 64 + 48 + j * 4)] = z;
    *(half4*)&Ws[SWZL(row, g * 64 + 48 + j * 4)] = z;
  }
#pragma unroll
  for (int i = 0; i < 24; ++i) {
    int fl = (i << 8) + t;
    int b = fl / 192, rem = fl % 192;
    int c = rem >> 6, rem2 = rem & 63;
    int a = rem2 >> 4, fi = (rem2 >> 2) & 3, bq = rem2 & 3;
    float4 v = *(const float4*)(x + ((size_t)(b0 + b) * 3 + c) * 1024 +
                                (p2 * 16 + a * 4 + fi) * 32 + q2 * 16 + bq * 4);
    half4 h;
    h[0] = (f16)v.x; h[1] = (f16)v.y; h[2] = (f16)v.z; h[3] = (f16)v.w;
    *(half4*)&Xs[SWZL(b, (a * 4 + bq) * 64 + c * 16 + fi * 4)] = h;
  }
#pragma unroll
  for (int i = 0; i < 24; ++i) {
    int fl = (i << 8) + t;
    int o = fl / 192, rem = fl % 192;
    int c = rem >> 6, rem2 = rem & 63;
    int g = rem2 >> 2, f4 = rem2 & 3;
    float4 v = *(const float4*)(w1 + (size_t)(o0 + o) * 3072 + c * 1024 +
                                (p2 * 4 + (g >> 2)) * 128 + (q2 * 4 + (g & 3)) * 16 + f4 * 4);
    half4 h;
    h[0] = (f16)v.x; h[1] = (f16)v.y; h[2] = (f16)v.z; h[3] = (f16)v.w;
    *(half4*)&Ws[SWZL(o, g * 64 + c * 16 + f4 * 4)] = h;
  }
  __syncthreads();

  const int wv = t >> 6, ln = t & 63;
  const int bw = wv >> 1, ow = wv & 1;
  const int frow = ln & 15, fr4 = ln >> 4;
  f32x4 acc[16] = {};
#pragma unroll
  for (int g = 0; g < 16; ++g) {
#pragma unroll
    for (int ks = 0; ks < 2; ++ks) {
      half8 a = *(const half8*)&Xs[SWZL(bw * 16 + frow, g * 64 + ks * 32 + fr4 * 8)];
      half8 b = *(const half8*)&Ws[SWZL(ow * 16 + frow, g * 64 + ks * 32 + fr4 * 8)];
      acc[g] = __builtin_amdgcn_mfma_f32_16x16x32_f16(a, b, acc[g], 0, 0, 0);
    }
  }
  f16* A2b = A2 + (size_t)s2 * 128 * 8192;
#pragma unroll
  for (int r = 0; r < 4; ++r) {
    int b = b0 + bw * 16 + fr4 * 4 + r;
    int o = o0 + ow * 16 + frow;
    f16 tmp[16];
#pragma unroll
    for (int g = 0; g < 16; ++g)
      tmp[g] = (f16)fmaxf(acc[g][r] * 0.14433756729740643f, 0.f);  // 1/sqrt(48)
    f16* dst = A2b + (size_t)b * 8192 + o * 16;
    *(half8*)dst = *(half8*)&tmp[0];
    *(half8*)(dst + 8) = *(half8*)&tmp[8];
  }
}

// gemm0: 512 blocks x 512 threads; tile M=128 x N=128, K-step 32, splitK=32.
// bid = s*128 + kc*4 + n (s-siblings share bid%8 -> same XCD).
// LDS: As[2][128*32] f16 (16 KB) + Bs[2][128*32] f32 (32 KB) = 48 KB -> 2 blocks/CU.
__global__ __launch_bounds__(512) void gemm0(const f16* __restrict__ A,
                                             const float* __restrict__ W,
                                             f16* __restrict__ P) {
  __shared__ __align__(16) f16 As[2][128 * 32];
  __shared__ __align__(16) float Bs[2][128 * 32];
  const int t = threadIdx.x;
  const int bid = blockIdx.x;
  constexpr int AK = 8192, ITERS = 8;  // K-chunk 256, step 32
  const int s = bid >> 7;
  const int kc = (bid >> 2) & 31;
  const int n = bid & 3;
  const int kb0 = kc * 256;
  const f16* Ab = A + (size_t)s * 128 * AK + kb0;
  const int o0 = n << 7;

  const int wv = t >> 6, ln = t & 63;

  // A: 128 rows x 4 granules (16B) -> 1 load/thread. r = t>>2, g0 = ln&3.
  // B: 128 rows x 8 granules -> 2 loads/thread. r = (t>>3) + j*64, g0 = ln&7.
#define STAGE(IT, BUF)                                                          \
  {                                                                             \
    {                                                                           \
      int r = t >> 2;                                                           \
      int sg = (ln & 3) ^ (r & 3);                                              \
      GLOAD_LDS16(Ab + (size_t)r * AK + ((IT) << 5) + (sg << 3),                \
                  &As[BUF][(wv * 16) << 5]);                                    \
    }                                                                           \
    _Pragma("unroll") for (int jj = 0; jj < 2; ++jj) {                          \
      int r = (t >> 3) + jj * 64;                                               \
      int sg = (ln & 7) ^ (r & 7);                                              \
      int k = kb0 + ((IT) << 5) + (sg << 2);                                    \
      const float* gp = W + (size_t)(o0 + r) * 32768 + ((k >> 4) << 6) +        \
                        (s << 4) + (k & 15);                                    \
      GLOAD_LDS16(gp, &Bs[BUF][(wv * 8 + jj * 64) << 5]);                       \
    }                                                                           \
  }

  const int wr = wv >> 2, wc = wv & 3;  // 2m x 4n waves, each 64 x 32
  const int frow = ln & 15, fr4 = ln >> 4;
  f32x4 acc[4][2] = {};

#define COMPUTE(BUF)                                                            \
  {                                                                             \
    half8 a[4];                                                                 \
    _Pragma("unroll") for (int mi = 0; mi < 4; ++mi) {                          \
      int r = wr * 64 + mi * 16 + frow;                                         \
      int gl = fr4 ^ (r & 3);                                                   \
      a[mi] = *(const half8*)&As[BUF][(r << 5) + (gl << 3)];                    \
    }                                                                           \
    _Pragma("unroll") for (int ni = 0; ni < 2; ++ni) {                          \
      int r = wc * 32 + ni * 16 + frow;                                         \
      int g0 = fr4 << 1;                                                        \
      float4 f0 = *(const float4*)&Bs[BUF][(r << 5) + ((g0 ^ (r & 7)) << 2)];   \
      float4 f1 = *(const float4*)&Bs[BUF][(r << 5) + (((g0 + 1) ^ (r & 7)) << 2)]; \
      half8 hb;                                                                 \
      hb[0] = (f16)f0.x; hb[1] = (f16)f0.y; hb[2] = (f16)f0.z; hb[3] = (f16)f0.w; \
      hb[4] = (f16)f1.x; hb[5] = (f16)f1.y; hb[6] = (f16)f1.z; hb[7] = (f16)f1.w; \
      _Pragma("unroll") for (int mi = 0; mi < 4; ++mi)                          \
        acc[mi][ni] = __builtin_amdgcn_mfma_f32_16x16x32_f16(a[mi], hb, acc[mi][ni], 0, 0, 0); \
    }                                                                           \
  }

  STAGE(0, 0)
#pragma unroll
  for (int it = 0; it < ITERS; ++it) {
    const int cur = it & 1;
    if (it + 1 < ITERS) {
      STAGE(it + 1, cur ^ 1)  // 3 more in flight (6 total)
      asm volatile("s_waitcnt vmcnt(3)" ::: "memory");  // cur's 3 landed
    } else {
      asm volatile("s_waitcnt vmcnt(0)" ::: "memory");
    }
    __builtin_amdgcn_s_barrier();
    __builtin_amdgcn_sched_barrier(0);
    COMPUTE(cur)
    __builtin_amdgcn_sched_barrier(0);
    __builtin_amdgcn_s_barrier();
  }

  f16* Pb = P + (size_t)((kc << 2) + s) * 65536;
#pragma unroll
  for (int mi = 0; mi < 4; ++mi)
#pragma unroll
    for (int ni = 0; ni < 2; ++ni)
#pragma unroll
      for (int r = 0; r < 4; ++r) {
        int gm = wr * 64 + mi * 16 + fr4 * 4 + r;
        int gn = o0 + wc * 32 + ni * 16 + frow;
        Pb[(size_t)gm * 512 + gn] = (f16)acc[mi][ni][r];
      }
#undef STAGE
#undef COMPUTE
}

// gemm1: 128 blocks, N=64 tile, K=2048, splitK=16; P3 fp16.
__global__ __launch_bounds__(256) void gemm1(const f16* __restrict__ A,
                                             const float* __restrict__ W,
                                             f16* __restrict__ P) {
  __shared__ __align__(16) f16 As[2][128 * 64];
  __shared__ __align__(16) float Bs[2][64 * 64];
  const int t = threadIdx.x;
  const int bid = blockIdx.x;
  constexpr int AK = 2048, ITERS = 2;
  const int kc = bid >> 3;
  const int n = bid & 7;
  const int kb0 = kc * (ITERS * 64);
  const f16* Ab = A + kb0;
  const int o0 = n << 6;
  const int wv = t >> 6, ln = t & 63;
  const int a_r = (ln >> 3), a_sg0 = ln & 7;
  const int b_r = (ln >> 4), b_sg0 = ln & 15;

#define STAGE(IT, BUF)                                                          \
  {                                                                             \
    _Pragma("unroll") for (int jj = 0; jj < 4; ++jj) {                          \
      int rbase = wv * 32 + jj * 8;                                             \
      int r = rbase + a_r;                                                      \
      int sg = a_sg0 ^ (r & 7);                                                 \
      GLOAD_LDS16(Ab + (size_t)r * AK + ((IT) << 6) + (sg << 3),                \
                  &As[BUF][rbase << 6]);                                        \
    }                                                                           \
    _Pragma("unroll") for (int jj = 0; jj < 4; ++jj) {                          \
      int rbase = wv * 16 + jj * 4;                                             \
      int r = rbase + b_r;                                                      \
      int sg = b_sg0 ^ (r & 7);                                                 \
      const float* gp = W + (size_t)(o0 + r) * 2048 + kb0 + ((IT) << 6) + (sg << 2); \
      GLOAD_LDS16(gp, &Bs[BUF][rbase << 6]);                                    \
    }                                                                           \
  }

  const int wr = wv >> 1, wc = wv & 1;
  const int frow = ln & 15, fr4 = ln >> 4;
  f32x4 acc[4][2] = {};

#define COMPUTE(BUF)                                                            \
  _Pragma("unroll") for (int ks = 0; ks < 2; ++ks) {                            \
    half8 a[4];                                                                 \
    _Pragma("unroll") for (int mi = 0; mi < 4; ++mi) {                          \
      int r = wr * 64 + mi * 16 + frow;                                         \
      int gl = ((ks << 2) + fr4) ^ (r & 7);                                     \
      a[mi] = *(const half8*)&As[BUF][(r << 6) + (gl << 3)];                    \
    }                                                                           \
    _Pragma("unroll") for (int ni = 0; ni < 2; ++ni) {                          \
      int r = wc * 32 + ni * 16 + frow;                                         \
      int s0 = (ks << 3) + (fr4 << 1);                                          \
      float4 f0 = *(const float4*)&Bs[BUF][(r << 6) + ((s0 ^ (r & 7)) << 2)];   \
      float4 f1 = *(const float4*)&Bs[BUF][(r << 6) + (((s0 + 1) ^ (r & 7)) << 2)]; \
      half8 hb;                                                                 \
      hb[0] = (f16)f0.x; hb[1] = (f16)f0.y; hb[2] = (f16)f0.z; hb[3] = (f16)f0.w; \
      hb[4] = (f16)f1.x; hb[5] = (f16)f1.y; hb[6] = (f16)f1.z; hb[7] = (f16)f1.w; \
      _Pragma("unroll") for (int mi = 0; mi < 4; ++mi)                          \
        acc[mi][ni] = __builtin_amdgcn_mfma_f32_16x16x32_f16(a[mi], hb, acc[mi][ni], 0, 0, 0); \
    }                                                                           \
  }

  STAGE(0, 0)
#pragma unroll
  for (int it = 0; it < ITERS; ++it) {
    const int cur = it & 1;
    if (it + 1 < ITERS) {
      STAGE(it + 1, cur ^ 1)
      asm volatile("s_waitcnt vmcnt(8)" ::: "memory");
    } else {
      asm volatile("s_waitcnt vmcnt(0)" ::: "memory");
    }
    __builtin_amdgcn_s_barrier();
    __builtin_amdgcn_sched_barrier(0);
    COMPUTE(cur)
    __builtin_amdgcn_sched_barrier(0);
    __builtin_amdgcn_s_barrier();
  }

  f16* Pb = P + (size_t)kc * 65536;
#pragma unroll
  for (int mi = 0; mi < 4; ++mi)
#pragma unroll
    for (int ni = 0; ni < 2; ++ni)
#pragma unroll
      for (int r = 0; r < 4; ++r) {
        int gm = wr * 64 + mi * 16 + fr4 * 4 + r;
        int gn = o0 + wc * 32 + ni * 16 + frow;
        Pb[(size_t)gm * 512 + gn] = (f16)acc[mi][ni][r];
      }
#undef STAGE
#undef COMPUTE
}

__global__ __launch_bounds__(256) void reduce2(const f16* __restrict__ P2,
                                               f16* __restrict__ A3) {
  int idx = blockIdx.x * 256 + threadIdx.x;
  int og = idx & 127, b = idx >> 7;
  f16 outv[16];
#pragma unroll
  for (int s = 0; s < 4; ++s) {
    float a0 = 0.f, a1 = 0.f, a2 = 0.f, a3 = 0.f;
#pragma unroll
    for (int kc = 0; kc < 32; ++kc) {
      half4 v = *(const half4*)(P2 + (size_t)((kc << 2) + s) * 65536 + b * 512 + og * 4);
      a0 += (float)v[0]; a1 += (float)v[1]; a2 += (float)v[2]; a3 += (float)v[3];
    }
    outv[0 * 4 + s] = (f16)fmaxf(a0 * 0.011048543456039805f, 0.f);  // 1/sqrt(8192)
    outv[1 * 4 + s] = (f16)fmaxf(a1 * 0.011048543456039805f, 0.f);
    outv[2 * 4 + s] = (f16)fmaxf(a2 * 0.011048543456039805f, 0.f);
    outv[3 * 4 + s] = (f16)fmaxf(a3 * 0.011048543456039805f, 0.f);
  }
  f16* dst = A3 + (size_t)b * 2048 + og * 16;
  *(half8*)dst = *(half8*)&outv[0];
  *(half8*)(dst + 8) = *(half8*)&outv[8];
}

__global__ __launch_bounds__(256) void out_fused(const f16* __restrict__ P3,
                                                 const float* __restrict__ beta,
                                                 float* __restrict__ out) {
  __shared__ float red[4];
  const int b = blockIdx.x, t = threadIdx.x;
  float acc = 0.f;
#pragma unroll
  for (int oi = 0; oi < 2; ++oi) {
    int o = (oi << 8) + t;
    float v = 0.f;
#pragma unroll
    for (int kc = 0; kc < 16; ++kc) v += (float)P3[(size_t)kc * 65536 + b * 512 + o];
    acc += fmaxf(v * 0.022097086912079608f, 0.f) * beta[o];  // 1/sqrt(2048)
  }
#pragma unroll
  for (int off = 32; off > 0; off >>= 1) acc += __shfl_down(acc, off);
  if ((t & 63) == 0) red[t >> 6] = acc;
  __syncthreads();
  if (t == 0) out[b] = (red[0] + red[1] + red[2] + red[3]) * 0.044194173824159216f;
}

extern "C" void kernel_launch(void* const* d_in, const int* in_sizes, int n_in,
                              void* d_out, int out_size, void* d_ws, size_t ws_size,
                              hipStream_t stream) {
  const float* x    = (const float*)d_in[0];
  const float* w1   = (const float*)d_in[1];
  const float* w2   = (const float*)d_in[2];
  const float* w3   = (const float*)d_in[3];
  const float* beta = (const float*)d_in[4];
  float* out = (float*)d_out;

  char* wsb = (char*)d_ws;
  f16* A2 = (f16*)wsb;                                     // 8 MiB
  f16* P2 = (f16*)(wsb + (8ull << 20));                    // 16 MiB (128 slices fp16)
  f16* A3 = (f16*)(wsb + (24ull << 20));                   // 0.5 MiB
  f16* P3 = (f16*)(wsb + (24ull << 20) + (1ull << 19));    // 2 MiB

  l1_mfma<<<dim3(16, 4, 4), 256, 0, stream>>>(x, w1, A2);
  gemm0<<<512, 512, 0, stream>>>(A2, w2, P2);
  reduce2<<<64, 256, 0, stream>>>(P2, A3);
  gemm1<<<128, 256, 0, stream>>>(A3, w3, P3);
  out_fused<<<128, 256, 0, stream>>>(P3, beta, out);
}

// Round 20
// 45.309 us; speedup vs baseline: 1.0592x; 1.0592x over previous
//
#include <hip/hip_runtime.h>

// LocNet2d on MFMA fp16, 5 dispatches (R18 structure; gemm0 v3 = fp16-B-in-LDS):
//   l1_mfma: R12-v3 (s2-cell block, staged once, coalesced A2 stores)
//   gemm0:   per-s GEMM M=128,N=512,K=8192, splitK=16, TILE N=128, K-step 64,
//            256 blocks x 512 thr. A via global_load_lds (fp16); B reg-staged:
//            float4 loads issued with prefetch, cvt fp16 + ds_write after compute
//            (T14 split). LDS 64 KB -> 2 blocks/CU. P2 fp16.
//   reduce2: fp16 P2 -> fp32 accum -> A3 fp16, coalesced.
//   gemm1:   128 blocks, N=64, splitK=16 -> P3 fp16
//   out:     reduce P3 + head.

typedef _Float16 f16;
typedef _Float16 half8 __attribute__((ext_vector_type(8)));
typedef _Float16 half4 __attribute__((ext_vector_type(4)));
typedef float f32x4 __attribute__((ext_vector_type(4)));

#define SWZ(r, c) ((((r) << 6) + (c)) ^ (((r) & 7) << 3))
#define SWZL(r, c) ((((r) << 10) + (c)) ^ (((r) & 7) << 3))

#define GLOAD_LDS16(G, L)                                                     \
  __builtin_amdgcn_global_load_lds(                                           \
      (const __attribute__((address_space(1))) void*)(G),                     \
      (__attribute__((address_space(3))) void*)(L), 16, 0, 0)

__global__ __launch_bounds__(256) void l1_mfma(const float* __restrict__ x,
                                               const float* __restrict__ w1,
                                               f16* __restrict__ A2) {
  const int o0 = blockIdx.x << 5;
  const int s2 = blockIdx.y;
  const int b0 = blockIdx.z << 5;
  const int p2 = s2 >> 1, q2 = s2 & 1;
  __shared__ __align__(16) f16 Xs[32 * 1024];  // 64 KB
  __shared__ __align__(16) f16 Ws[32 * 1024];  // 64 KB
  const int t = threadIdx.x;
#pragma unroll
  for (int i = 0; i < 8; ++i) {
    int e = (i << 8) + t;
    int row = e >> 6, rem = e & 63, g = rem >> 2, j = rem & 3;
    half4 z = {};
    *(half4*)&Xs[SWZL(row, g * 64 + 48 + j * 4)] = z;
    *(half4*)&Ws[SWZL(row, g * 64 + 48 + j * 4)] = z;
  }
#pragma unroll
  for (int i = 0; i < 24; ++i) {
    int fl = (i << 8) + t;
    int b = fl / 192, rem = fl % 192;
    int c = rem >> 6, rem2 = rem & 63;
    int a = rem2 >> 4, fi = (rem2 >> 2) & 3, bq = rem2 & 3;
    float4 v = *(const float4*)(x + ((size_t)(b0 + b) * 3 + c) * 1024 +
                                (p2 * 16 + a * 4 + fi) * 32 + q2 * 16 + bq * 4);
    half4 h;
    h[0] = (f16)v.x; h[1] = (f16)v.y; h[2] = (f16)v.z; h[3] = (f16)v.w;
    *(half4*)&Xs[SWZL(b, (a * 4 + bq) * 64 + c * 16 + fi * 4)] = h;
  }
#pragma unroll
  for (int i = 0; i < 24; ++i) {
    int fl = (i << 8) + t;
    int o = fl / 192, rem = fl % 192;
    int c = rem >> 6, rem2 = rem & 63;
    int g = rem2 >> 2, f4 = rem2 & 3;
    float4 v = *(const float4*)(w1 + (size_t)(o0 + o) * 3072 + c * 1024 +
                                (p2 * 4 + (g >> 2)) * 128 + (q2 * 4 + (g & 3)) * 16 + f4 * 4);
    half4 h;
    h[0] = (f16)v.x; h[1] = (f16)v.y; h[2] = (f16)v.z; h[3] = (f16)v.w;
    *(half4*)&Ws[SWZL(o, g * 64 + c * 16 + f4 * 4)] = h;
  }
  __syncthreads();

  const int wv = t >> 6, ln = t & 63;
  const int bw = wv >> 1, ow = wv & 1;
  const int frow = ln & 15, fr4 = ln >> 4;
  f32x4 acc[16] = {};
#pragma unroll
  for (int g = 0; g < 16; ++g) {
#pragma unroll
    for (int ks = 0; ks < 2; ++ks) {
      half8 a = *(const half8*)&Xs[SWZL(bw * 16 + frow, g * 64 + ks * 32 + fr4 * 8)];
      half8 b = *(const half8*)&Ws[SWZL(ow * 16 + frow, g * 64 + ks * 32 + fr4 * 8)];
      acc[g] = __builtin_amdgcn_mfma_f32_16x16x32_f16(a, b, acc[g], 0, 0, 0);
    }
  }
  f16* A2b = A2 + (size_t)s2 * 128 * 8192;
#pragma unroll
  for (int r = 0; r < 4; ++r) {
    int b = b0 + bw * 16 + fr4 * 4 + r;
    int o = o0 + ow * 16 + frow;
    f16 tmp[16];
#pragma unroll
    for (int g = 0; g < 16; ++g)
      tmp[g] = (f16)fmaxf(acc[g][r] * 0.14433756729740643f, 0.f);  // 1/sqrt(48)
    f16* dst = A2b + (size_t)b * 8192 + o * 16;
    *(half8*)dst = *(half8*)&tmp[0];
    *(half8*)(dst + 8) = *(half8*)&tmp[8];
  }
}

// gemm0 v3: 256 blocks x 512 threads; tile M=128 x N=128; bid = s*64 + kc*4 + n.
// A: global_load_lds fp16 (2/thread). B: reg-staged float4 (4/thread, issued with
// prefetch) -> cvt fp16 -> ds_write after compute. LDS 64 KB -> 2 blocks/CU.
__global__ __launch_bounds__(512, 4) void gemm0(const f16* __restrict__ A,
                                                const float* __restrict__ W,
                                                f16* __restrict__ P) {
  __shared__ __align__(16) f16 As[2][128 * 64];  // 32 KB
  __shared__ __align__(16) f16 Bs[2][128 * 64];  // 32 KB
  const int t = threadIdx.x;
  const int bid = blockIdx.x;
  constexpr int AK = 8192, ITERS = 8;
  const int s = bid >> 6;
  const int kc = (bid >> 2) & 15;
  const int n = bid & 3;
  const int kb0 = kc * 512;
  const f16* Ab = A + (size_t)s * 128 * AK + kb0;
  const int o0 = n << 7;

  const int wv = t >> 6, ln = t & 63;
  const int br = t >> 4, bslot = t & 15;  // B: rows i*32+br, float4 slot
  float4 breg[4];

  // B loads FIRST (so vmcnt(2) later retires exactly these 4), then A DMA.
#define B_LOAD(IT)                                                              \
  _Pragma("unroll") for (int i = 0; i < 4; ++i) {                               \
    int r = i * 32 + br;                                                        \
    int k = kb0 + ((IT) << 6) + (bslot << 2);                                   \
    breg[i] = *(const float4*)(W + (size_t)(o0 + r) * 32768 + ((k >> 4) << 6) + \
                               (s << 4) + (k & 15));                            \
  }

#define A_DMA(IT, BUF)                                                          \
  _Pragma("unroll") for (int jj = 0; jj < 2; ++jj) {                            \
    int rbase = wv * 16 + jj * 8;                                               \
    int r = rbase + (ln >> 3);                                                  \
    int sg = (ln & 7) ^ (r & 7);                                                \
    GLOAD_LDS16(Ab + (size_t)r * AK + ((IT) << 6) + (sg << 3),                  \
                &As[BUF][rbase << 6]);                                          \
  }

#define B_WRITE(BUF)                                                            \
  _Pragma("unroll") for (int i = 0; i < 4; ++i) {                               \
    int r = i * 32 + br;                                                        \
    half4 h4;                                                                   \
    h4[0] = (f16)breg[i].x; h4[1] = (f16)breg[i].y;                             \
    h4[2] = (f16)breg[i].z; h4[3] = (f16)breg[i].w;                             \
    int off = (r << 6) + (((bslot >> 1) ^ (r & 7)) << 3) + ((bslot & 1) << 2);  \
    *(half4*)&Bs[BUF][off] = h4;                                                \
  }

  const int wr = wv >> 2, wc = wv & 3;  // 2m x 4n waves, each 64 x 32
  const int frow = ln & 15, fr4 = ln >> 4;
  f32x4 acc[4][2] = {};

#define COMPUTE(BUF)                                                            \
  _Pragma("unroll") for (int ks = 0; ks < 2; ++ks) {                            \
    half8 a[4];                                                                 \
    _Pragma("unroll") for (int mi = 0; mi < 4; ++mi) {                          \
      int r = wr * 64 + mi * 16 + frow;                                         \
      int gl = ((ks << 2) + fr4) ^ (r & 7);                                     \
      a[mi] = *(const half8*)&As[BUF][(r << 6) + (gl << 3)];                    \
    }                                                                           \
    _Pragma("unroll") for (int ni = 0; ni < 2; ++ni) {                          \
      int r = wc * 32 + ni * 16 + frow;                                         \
      int gl = ((ks << 2) + fr4) ^ (r & 7);                                     \
      half8 hb = *(const half8*)&Bs[BUF][(r << 6) + (gl << 3)];                 \
      _Pragma("unroll") for (int mi = 0; mi < 4; ++mi)                          \
        acc[mi][ni] = __builtin_amdgcn_mfma_f32_16x16x32_f16(a[mi], hb, acc[mi][ni], 0, 0, 0); \
    }                                                                           \
  }

  // prologue: tile 0
  B_LOAD(0)
  A_DMA(0, 0)
  asm volatile("s_waitcnt vmcnt(2)" ::: "memory");  // B(0) regs ready (A dma in flight)
  B_WRITE(0)
#pragma unroll
  for (int it = 0; it < ITERS; ++it) {
    const int cur = it & 1;
    if (it + 1 < ITERS) {
      B_LOAD(it + 1)        // 4 reg loads (oldest of this batch)
      A_DMA(it + 1, cur ^ 1)  // 2 dma
      asm volatile("s_waitcnt vmcnt(6) lgkmcnt(0)" ::: "memory");  // A(cur) landed; my Bs[cur] writes done
    } else {
      asm volatile("s_waitcnt vmcnt(0) lgkmcnt(0)" ::: "memory");
    }
    __builtin_amdgcn_s_barrier();
    __builtin_amdgcn_sched_barrier(0);
    COMPUTE(cur)
    __builtin_amdgcn_sched_barrier(0);
    if (it + 1 < ITERS) {
      asm volatile("s_waitcnt vmcnt(2)" ::: "memory");  // B(it+1) regs ready (A dma in flight)
      B_WRITE(cur ^ 1)
    }
    __builtin_amdgcn_s_barrier();  // all reads of cur done before re-stage
  }

  f16* Pb = P + (size_t)((kc << 2) + s) * 65536;
#pragma unroll
  for (int mi = 0; mi < 4; ++mi)
#pragma unroll
    for (int ni = 0; ni < 2; ++ni)
#pragma unroll
      for (int r = 0; r < 4; ++r) {
        int gm = wr * 64 + mi * 16 + fr4 * 4 + r;
        int gn = o0 + wc * 32 + ni * 16 + frow;
        Pb[(size_t)gm * 512 + gn] = (f16)acc[mi][ni][r];
      }
#undef B_LOAD
#undef A_DMA
#undef B_WRITE
#undef COMPUTE
}

// gemm1: 128 blocks, N=64 tile, K=2048, splitK=16; P3 fp16. (R18 verbatim)
__global__ __launch_bounds__(256) void gemm1(const f16* __restrict__ A,
                                             const float* __restrict__ W,
                                             f16* __restrict__ P) {
  __shared__ __align__(16) f16 As[2][128 * 64];
  __shared__ __align__(16) float Bs[2][64 * 64];
  const int t = threadIdx.x;
  const int bid = blockIdx.x;
  constexpr int AK = 2048, ITERS = 2;
  const int kc = bid >> 3;
  const int n = bid & 7;
  const int kb0 = kc * (ITERS * 64);
  const f16* Ab = A + kb0;
  const int o0 = n << 6;
  const int wv = t >> 6, ln = t & 63;
  const int a_r = (ln >> 3), a_sg0 = ln & 7;
  const int b_r = (ln >> 4), b_sg0 = ln & 15;

#define STAGE(IT, BUF)                                                          \
  {                                                                             \
    _Pragma("unroll") for (int jj = 0; jj < 4; ++jj) {                          \
      int rbase = wv * 32 + jj * 8;                                             \
      int r = rbase + a_r;                                                      \
      int sg = a_sg0 ^ (r & 7);                                                 \
      GLOAD_LDS16(Ab + (size_t)r * AK + ((IT) << 6) + (sg << 3),                \
                  &As[BUF][rbase << 6]);                                        \
    }                                                                           \
    _Pragma("unroll") for (int jj = 0; jj < 4; ++jj) {                          \
      int rbase = wv * 16 + jj * 4;                                             \
      int r = rbase + b_r;                                                      \
      int sg = b_sg0 ^ (r & 7);                                                 \
      const float* gp = W + (size_t)(o0 + r) * 2048 + kb0 + ((IT) << 6) + (sg << 2); \
      GLOAD_LDS16(gp, &Bs[BUF][rbase << 6]);                                    \
    }                                                                           \
  }

  const int wr = wv >> 1, wc = wv & 1;
  const int frow = ln & 15, fr4 = ln >> 4;
  f32x4 acc[4][2] = {};

#define COMPUTE(BUF)                                                            \
  _Pragma("unroll") for (int ks = 0; ks < 2; ++ks) {                            \
    half8 a[4];                                                                 \
    _Pragma("unroll") for (int mi = 0; mi < 4; ++mi) {                          \
      int r = wr * 64 + mi * 16 + frow;                                         \
      int gl = ((ks << 2) + fr4) ^ (r & 7);                                     \
      a[mi] = *(const half8*)&As[BUF][(r << 6) + (gl << 3)];                    \
    }                                                                           \
    _Pragma("unroll") for (int ni = 0; ni < 2; ++ni) {                          \
      int r = wc * 32 + ni * 16 + frow;                                         \
      int s0 = (ks << 3) + (fr4 << 1);                                          \
      float4 f0 = *(const float4*)&Bs[BUF][(r << 6) + ((s0 ^ (r & 7)) << 2)];   \
      float4 f1 = *(const float4*)&Bs[BUF][(r << 6) + (((s0 + 1) ^ (r & 7)) << 2)]; \
      half8 hb;                                                                 \
      hb[0] = (f16)f0.x; hb[1] = (f16)f0.y; hb[2] = (f16)f0.z; hb[3] = (f16)f0.w; \
      hb[4] = (f16)f1.x; hb[5] = (f16)f1.y; hb[6] = (f16)f1.z; hb[7] = (f16)f1.w; \
      _Pragma("unroll") for (int mi = 0; mi < 4; ++mi)                          \
        acc[mi][ni] = __builtin_amdgcn_mfma_f32_16x16x32_f16(a[mi], hb, acc[mi][ni], 0, 0, 0); \
    }                                                                           \
  }

  STAGE(0, 0)
#pragma unroll
  for (int it = 0; it < ITERS; ++it) {
    const int cur = it & 1;
    if (it + 1 < ITERS) {
      STAGE(it + 1, cur ^ 1)
      asm volatile("s_waitcnt vmcnt(8)" ::: "memory");
    } else {
      asm volatile("s_waitcnt vmcnt(0)" ::: "memory");
    }
    __builtin_amdgcn_s_barrier();
    __builtin_amdgcn_sched_barrier(0);
    COMPUTE(cur)
    __builtin_amdgcn_sched_barrier(0);
    __builtin_amdgcn_s_barrier();
  }

  f16* Pb = P + (size_t)kc * 65536;
#pragma unroll
  for (int mi = 0; mi < 4; ++mi)
#pragma unroll
    for (int ni = 0; ni < 2; ++ni)
#pragma unroll
      for (int r = 0; r < 4; ++r) {
        int gm = wr * 64 + mi * 16 + fr4 * 4 + r;
        int gn = o0 + wc * 32 + ni * 16 + frow;
        Pb[(size_t)gm * 512 + gn] = (f16)acc[mi][ni][r];
      }
#undef STAGE
#undef COMPUTE
}

__global__ __launch_bounds__(256) void reduce2(const f16* __restrict__ P2,
                                               f16* __restrict__ A3) {
  int idx = blockIdx.x * 256 + threadIdx.x;
  int og = idx & 127, b = idx >> 7;
  f16 outv[16];
#pragma unroll
  for (int s = 0; s < 4; ++s) {
    float a0 = 0.f, a1 = 0.f, a2 = 0.f, a3 = 0.f;
#pragma unroll
    for (int kc = 0; kc < 16; ++kc) {
      half4 v = *(const half4*)(P2 + (size_t)((kc << 2) + s) * 65536 + b * 512 + og * 4);
      a0 += (float)v[0]; a1 += (float)v[1]; a2 += (float)v[2]; a3 += (float)v[3];
    }
    outv[0 * 4 + s] = (f16)fmaxf(a0 * 0.011048543456039805f, 0.f);  // 1/sqrt(8192)
    outv[1 * 4 + s] = (f16)fmaxf(a1 * 0.011048543456039805f, 0.f);
    outv[2 * 4 + s] = (f16)fmaxf(a2 * 0.011048543456039805f, 0.f);
    outv[3 * 4 + s] = (f16)fmaxf(a3 * 0.011048543456039805f, 0.f);
  }
  f16* dst = A3 + (size_t)b * 2048 + og * 16;
  *(half8*)dst = *(half8*)&outv[0];
  *(half8*)(dst + 8) = *(half8*)&outv[8];
}

__global__ __launch_bounds__(256) void out_fused(const f16* __restrict__ P3,
                                                 const float* __restrict__ beta,
                                                 float* __restrict__ out) {
  __shared__ float red[4];
  const int b = blockIdx.x, t = threadIdx.x;
  float acc = 0.f;
#pragma unroll
  for (int oi = 0; oi < 2; ++oi) {
    int o = (oi << 8) + t;
    float v = 0.f;
#pragma unroll
    for (int kc = 0; kc < 16; ++kc) v += (float)P3[(size_t)kc * 65536 + b * 512 + o];
    acc += fmaxf(v * 0.022097086912079608f, 0.f) * beta[o];  // 1/sqrt(2048)
  }
#pragma unroll
  for (int off = 32; off > 0; off >>= 1) acc += __shfl_down(acc, off);
  if ((t & 63) == 0) red[t >> 6] = acc;
  __syncthreads();
  if (t == 0) out[b] = (red[0] + red[1] + red[2] + red[3]) * 0.044194173824159216f;
}

extern "C" void kernel_launch(void* const* d_in, const int* in_sizes, int n_in,
                              void* d_out, int out_size, void* d_ws, size_t ws_size,
                              hipStream_t stream) {
  const float* x    = (const float*)d_in[0];
  const float* w1   = (const float*)d_in[1];
  const float* w2   = (const float*)d_in[2];
  const float* w3   = (const float*)d_in[3];
  const float* beta = (const float*)d_in[4];
  float* out = (float*)d_out;

  char* wsb = (char*)d_ws;
  f16* A2 = (f16*)wsb;                                     // 8 MiB
  f16* P2 = (f16*)(wsb + (8ull << 20));                    // 8 MiB (fp16, 64 slices)
  f16* A3 = (f16*)(wsb + (16ull << 20));                   // 0.5 MiB
  f16* P3 = (f16*)(wsb + (16ull << 20) + (1ull << 19));    // 2 MiB

  l1_mfma<<<dim3(16, 4, 4), 256, 0, stream>>>(x, w1, A2);
  gemm0<<<256, 512, 0, stream>>>(A2, w2, P2);
  reduce2<<<64, 256, 0, stream>>>(P2, A3);
  gemm1<<<128, 256, 0, stream>>>(A3, w3, P3);
  out_fused<<<128, 256, 0, stream>>>(P3, beta, out);
}

// Round 21
// 44.286 us; speedup vs baseline: 1.0837x; 1.0231x over previous
//
#include <hip/hip_runtime.h>

// LocNet2d on MFMA fp16, 5 dispatches (R18 best + gemm0 triple-buffer 2-ahead):
//   l1_mfma: R12-v3 (s2-cell block, staged once, coalesced A2 stores)
//   gemm0:   per-s GEMM M=128,N=512,K=8192, splitK=16, TILE N=128, K-step 64,
//            256 blocks x 512 thr, TRIPLE-buffered LDS (144 KB), 2 tiles ahead,
//            counted vmcnt(12) -> loads span 2 barriers. P2 fp16.
//   reduce2: fp16 P2 -> fp32 accum -> A3 fp16, coalesced.
//   gemm1:   128 blocks, N=64, splitK=16 -> P3 fp16
//   out:     reduce P3 + head.

typedef _Float16 f16;
typedef _Float16 half8 __attribute__((ext_vector_type(8)));
typedef _Float16 half4 __attribute__((ext_vector_type(4)));
typedef float f32x4 __attribute__((ext_vector_type(4)));

#define SWZ(r, c) ((((r) << 6) + (c)) ^ (((r) & 7) << 3))
#define SWZL(r, c) ((((r) << 10) + (c)) ^ (((r) & 7) << 3))

#define GLOAD_LDS16(G, L)                                                     \
  __builtin_amdgcn_global_load_lds(                                           \
      (const __attribute__((address_space(1))) void*)(G),                     \
      (__attribute__((address_space(3))) void*)(L), 16, 0, 0)

__global__ __launch_bounds__(256) void l1_mfma(const float* __restrict__ x,
                                               const float* __restrict__ w1,
                                               f16* __restrict__ A2) {
  const int o0 = blockIdx.x << 5;
  const int s2 = blockIdx.y;
  const int b0 = blockIdx.z << 5;
  const int p2 = s2 >> 1, q2 = s2 & 1;
  __shared__ __align__(16) f16 Xs[32 * 1024];  // 64 KB
  __shared__ __align__(16) f16 Ws[32 * 1024];  // 64 KB
  const int t = threadIdx.x;
#pragma unroll
  for (int i = 0; i < 8; ++i) {
    int e = (i << 8) + t;
    int row = e >> 6, rem = e & 63, g = rem >> 2, j = rem & 3;
    half4 z = {};
    *(half4*)&Xs[SWZL(row, g * 64 + 48 + j * 4)] = z;
    *(half4*)&Ws[SWZL(row, g * 64 + 48 + j * 4)] = z;
  }
#pragma unroll
  for (int i = 0; i < 24; ++i) {
    int fl = (i << 8) + t;
    int b = fl / 192, rem = fl % 192;
    int c = rem >> 6, rem2 = rem & 63;
    int a = rem2 >> 4, fi = (rem2 >> 2) & 3, bq = rem2 & 3;
    float4 v = *(const float4*)(x + ((size_t)(b0 + b) * 3 + c) * 1024 +
                                (p2 * 16 + a * 4 + fi) * 32 + q2 * 16 + bq * 4);
    half4 h;
    h[0] = (f16)v.x; h[1] = (f16)v.y; h[2] = (f16)v.z; h[3] = (f16)v.w;
    *(half4*)&Xs[SWZL(b, (a * 4 + bq) * 64 + c * 16 + fi * 4)] = h;
  }
#pragma unroll
  for (int i = 0; i < 24; ++i) {
    int fl = (i << 8) + t;
    int o = fl / 192, rem = fl % 192;
    int c = rem >> 6, rem2 = rem & 63;
    int g = rem2 >> 2, f4 = rem2 & 3;
    float4 v = *(const float4*)(w1 + (size_t)(o0 + o) * 3072 + c * 1024 +
                                (p2 * 4 + (g >> 2)) * 128 + (q2 * 4 + (g & 3)) * 16 + f4 * 4);
    half4 h;
    h[0] = (f16)v.x; h[1] = (f16)v.y; h[2] = (f16)v.z; h[3] = (f16)v.w;
    *(half4*)&Ws[SWZL(o, g * 64 + c * 16 + f4 * 4)] = h;
  }
  __syncthreads();

  const int wv = t >> 6, ln = t & 63;
  const int bw = wv >> 1, ow = wv & 1;
  const int frow = ln & 15, fr4 = ln >> 4;
  f32x4 acc[16] = {};
#pragma unroll
  for (int g = 0; g < 16; ++g) {
#pragma unroll
    for (int ks = 0; ks < 2; ++ks) {
      half8 a = *(const half8*)&Xs[SWZL(bw * 16 + frow, g * 64 + ks * 32 + fr4 * 8)];
      half8 b = *(const half8*)&Ws[SWZL(ow * 16 + frow, g * 64 + ks * 32 + fr4 * 8)];
      acc[g] = __builtin_amdgcn_mfma_f32_16x16x32_f16(a, b, acc[g], 0, 0, 0);
    }
  }
  f16* A2b = A2 + (size_t)s2 * 128 * 8192;
#pragma unroll
  for (int r = 0; r < 4; ++r) {
    int b = b0 + bw * 16 + fr4 * 4 + r;
    int o = o0 + ow * 16 + frow;
    f16 tmp[16];
#pragma unroll
    for (int g = 0; g < 16; ++g)
      tmp[g] = (f16)fmaxf(acc[g][r] * 0.14433756729740643f, 0.f);  // 1/sqrt(48)
    f16* dst = A2b + (size_t)b * 8192 + o * 16;
    *(half8*)dst = *(half8*)&tmp[0];
    *(half8*)(dst + 8) = *(half8*)&tmp[8];
  }
}

// gemm0: 256 blocks x 512 thr; tile M=128 x N=128; bid = s*64 + kc*4 + n.
// Triple-buffered LDS (As 3x16 KB f16 + Bs 3x32 KB f32 = 144 KB), 2 tiles ahead:
// steady-state 12 loads in flight; vmcnt(12) retires the current tile's 6.
__global__ __launch_bounds__(512) void gemm0(const f16* __restrict__ A,
                                             const float* __restrict__ W,
                                             f16* __restrict__ P) {
  __shared__ __align__(16) f16 As[3][128 * 64];    // 48 KB
  __shared__ __align__(16) float Bs[3][128 * 64];  // 96 KB
  const int t = threadIdx.x;
  const int bid = blockIdx.x;
  constexpr int AK = 8192, ITERS = 8;
  const int s = bid >> 6;
  const int kc = (bid >> 2) & 15;
  const int n = bid & 3;
  const int kb0 = kc * 512;
  const f16* Ab = A + (size_t)s * 128 * AK + kb0;
  const int o0 = n << 7;

  const int wv = t >> 6, ln = t & 63;

#define STAGE(IT, BUF)                                                          \
  {                                                                             \
    _Pragma("unroll") for (int jj = 0; jj < 2; ++jj) { /* A: 2 loads */         \
      int rbase = wv * 16 + jj * 8;                                             \
      int r = rbase + (ln >> 3);                                                \
      int sg = (ln & 7) ^ (r & 7);                                              \
      GLOAD_LDS16(Ab + (size_t)r * AK + ((IT) << 6) + (sg << 3),                \
                  &As[BUF][rbase << 6]);                                        \
    }                                                                           \
    _Pragma("unroll") for (int jj = 0; jj < 4; ++jj) { /* B: 4 loads */         \
      int rbase = wv * 16 + jj * 4;                                             \
      int r = rbase + (ln >> 4);                                                \
      int sg = (ln & 15) ^ (r & 7);                                             \
      int k = kb0 + ((IT) << 6) + (sg << 2);                                    \
      const float* gp = W + (size_t)(o0 + r) * 32768 + ((k >> 4) << 6) +        \
                        (s << 4) + (k & 15);                                    \
      GLOAD_LDS16(gp, &Bs[BUF][rbase << 6]);                                    \
    }                                                                           \
  }

  const int wr = wv >> 2, wc = wv & 3;  // 2m x 4n waves, each 64 x 32
  const int frow = ln & 15, fr4 = ln >> 4;
  f32x4 acc[4][2] = {};

#define COMPUTE(BUF)                                                            \
  _Pragma("unroll") for (int ks = 0; ks < 2; ++ks) {                            \
    half8 a[4];                                                                 \
    _Pragma("unroll") for (int mi = 0; mi < 4; ++mi) {                          \
      int r = wr * 64 + mi * 16 + frow;                                         \
      int gl = ((ks << 2) + fr4) ^ (r & 7);                                     \
      a[mi] = *(const half8*)&As[BUF][(r << 6) + (gl << 3)];                    \
    }                                                                           \
    _Pragma("unroll") for (int ni = 0; ni < 2; ++ni) {                          \
      int r = wc * 32 + ni * 16 + frow;                                         \
      int s0 = (ks << 3) + (fr4 << 1);                                          \
      float4 f0 = *(const float4*)&Bs[BUF][(r << 6) + ((s0 ^ (r & 7)) << 2)];   \
      float4 f1 = *(const float4*)&Bs[BUF][(r << 6) + (((s0 + 1) ^ (r & 7)) << 2)]; \
      half8 hb;                                                                 \
      hb[0] = (f16)f0.x; hb[1] = (f16)f0.y; hb[2] = (f16)f0.z; hb[3] = (f16)f0.w; \
      hb[4] = (f16)f1.x; hb[5] = (f16)f1.y; hb[6] = (f16)f1.z; hb[7] = (f16)f1.w; \
      _Pragma("unroll") for (int mi = 0; mi < 4; ++mi)                          \
        acc[mi][ni] = __builtin_amdgcn_mfma_f32_16x16x32_f16(a[mi], hb, acc[mi][ni], 0, 0, 0); \
    }                                                                           \
  }

  STAGE(0, 0)
  STAGE(1, 1)  // 12 in flight
#pragma unroll
  for (int it = 0; it < ITERS; ++it) {
    const int cur = it % 3;
    if (it + 2 < ITERS) {
      STAGE(it + 2, (it + 2) % 3)  // 18 in flight
      asm volatile("s_waitcnt vmcnt(12)" ::: "memory");  // tile it's 6 landed
    } else if (it + 1 < ITERS) {
      asm volatile("s_waitcnt vmcnt(6)" ::: "memory");   // tail: tile it landed
    } else {
      asm volatile("s_waitcnt vmcnt(0)" ::: "memory");
    }
    __builtin_amdgcn_s_barrier();
    __builtin_amdgcn_sched_barrier(0);
    COMPUTE(cur)
    __builtin_amdgcn_sched_barrier(0);
    __builtin_amdgcn_s_barrier();  // reads of cur done before cur is re-staged (it+3)
  }

  f16* Pb = P + (size_t)((kc << 2) + s) * 65536;
#pragma unroll
  for (int mi = 0; mi < 4; ++mi)
#pragma unroll
    for (int ni = 0; ni < 2; ++ni)
#pragma unroll
      for (int r = 0; r < 4; ++r) {
        int gm = wr * 64 + mi * 16 + fr4 * 4 + r;
        int gn = o0 + wc * 32 + ni * 16 + frow;
        Pb[(size_t)gm * 512 + gn] = (f16)acc[mi][ni][r];
      }
#undef STAGE
#undef COMPUTE
}

// gemm1: 128 blocks, N=64 tile, K=2048, splitK=16; P3 fp16.
__global__ __launch_bounds__(256) void gemm1(const f16* __restrict__ A,
                                             const float* __restrict__ W,
                                             f16* __restrict__ P) {
  __shared__ __align__(16) f16 As[2][128 * 64];
  __shared__ __align__(16) float Bs[2][64 * 64];
  const int t = threadIdx.x;
  const int bid = blockIdx.x;
  constexpr int AK = 2048, ITERS = 2;
  const int kc = bid >> 3;
  const int n = bid & 7;
  const int kb0 = kc * (ITERS * 64);
  const f16* Ab = A + kb0;
  const int o0 = n << 6;
  const int wv = t >> 6, ln = t & 63;
  const int a_r = (ln >> 3), a_sg0 = ln & 7;
  const int b_r = (ln >> 4), b_sg0 = ln & 15;

#define STAGE(IT, BUF)                                                          \
  {                                                                             \
    _Pragma("unroll") for (int jj = 0; jj < 4; ++jj) {                          \
      int rbase = wv * 32 + jj * 8;                                             \
      int r = rbase + a_r;                                                      \
      int sg = a_sg0 ^ (r & 7);                                                 \
      GLOAD_LDS16(Ab + (size_t)r * AK + ((IT) << 6) + (sg << 3),                \
                  &As[BUF][rbase << 6]);                                        \
    }                                                                           \
    _Pragma("unroll") for (int jj = 0; jj < 4; ++jj) {                          \
      int rbase = wv * 16 + jj * 4;                                             \
      int r = rbase + b_r;                                                      \
      int sg = b_sg0 ^ (r & 7);                                                 \
      const float* gp = W + (size_t)(o0 + r) * 2048 + kb0 + ((IT) << 6) + (sg << 2); \
      GLOAD_LDS16(gp, &Bs[BUF][rbase << 6]);                                    \
    }                                                                           \
  }

  const int wr = wv >> 1, wc = wv & 1;
  const int frow = ln & 15, fr4 = ln >> 4;
  f32x4 acc[4][2] = {};

#define COMPUTE(BUF)                                                            \
  _Pragma("unroll") for (int ks = 0; ks < 2; ++ks) {                            \
    half8 a[4];                                                                 \
    _Pragma("unroll") for (int mi = 0; mi < 4; ++mi) {                          \
      int r = wr * 64 + mi * 16 + frow;                                         \
      int gl = ((ks << 2) + fr4) ^ (r & 7);                                     \
      a[mi] = *(const half8*)&As[BUF][(r << 6) + (gl << 3)];                    \
    }                                                                           \
    _Pragma("unroll") for (int ni = 0; ni < 2; ++ni) {                          \
      int r = wc * 32 + ni * 16 + frow;                                         \
      int s0 = (ks << 3) + (fr4 << 1);                                          \
      float4 f0 = *(const float4*)&Bs[BUF][(r << 6) + ((s0 ^ (r & 7)) << 2)];   \
      float4 f1 = *(const float4*)&Bs[BUF][(r << 6) + (((s0 + 1) ^ (r & 7)) << 2)]; \
      half8 hb;                                                                 \
      hb[0] = (f16)f0.x; hb[1] = (f16)f0.y; hb[2] = (f16)f0.z; hb[3] = (f16)f0.w; \
      hb[4] = (f16)f1.x; hb[5] = (f16)f1.y; hb[6] = (f16)f1.z; hb[7] = (f16)f1.w; \
      _Pragma("unroll") for (int mi = 0; mi < 4; ++mi)                          \
        acc[mi][ni] = __builtin_amdgcn_mfma_f32_16x16x32_f16(a[mi], hb, acc[mi][ni], 0, 0, 0); \
    }                                                                           \
  }

  STAGE(0, 0)
#pragma unroll
  for (int it = 0; it < ITERS; ++it) {
    const int cur = it & 1;
    if (it + 1 < ITERS) {
      STAGE(it + 1, cur ^ 1)
      asm volatile("s_waitcnt vmcnt(8)" ::: "memory");
    } else {
      asm volatile("s_waitcnt vmcnt(0)" ::: "memory");
    }
    __builtin_amdgcn_s_barrier();
    __builtin_amdgcn_sched_barrier(0);
    COMPUTE(cur)
    __builtin_amdgcn_sched_barrier(0);
    __builtin_amdgcn_s_barrier();
  }

  f16* Pb = P + (size_t)kc * 65536;
#pragma unroll
  for (int mi = 0; mi < 4; ++mi)
#pragma unroll
    for (int ni = 0; ni < 2; ++ni)
#pragma unroll
      for (int r = 0; r < 4; ++r) {
        int gm = wr * 64 + mi * 16 + fr4 * 4 + r;
        int gn = o0 + wc * 32 + ni * 16 + frow;
        Pb[(size_t)gm * 512 + gn] = (f16)acc[mi][ni][r];
      }
#undef STAGE
#undef COMPUTE
}

__global__ __launch_bounds__(256) void reduce2(const f16* __restrict__ P2,
                                               f16* __restrict__ A3) {
  int idx = blockIdx.x * 256 + threadIdx.x;
  int og = idx & 127, b = idx >> 7;
  f16 outv[16];
#pragma unroll
  for (int s = 0; s < 4; ++s) {
    float a0 = 0.f, a1 = 0.f, a2 = 0.f, a3 = 0.f;
#pragma unroll
    for (int kc = 0; kc < 16; ++kc) {
      half4 v = *(const half4*)(P2 + (size_t)((kc << 2) + s) * 65536 + b * 512 + og * 4);
      a0 += (float)v[0]; a1 += (float)v[1]; a2 += (float)v[2]; a3 += (float)v[3];
    }
    outv[0 * 4 + s] = (f16)fmaxf(a0 * 0.011048543456039805f, 0.f);  // 1/sqrt(8192)
    outv[1 * 4 + s] = (f16)fmaxf(a1 * 0.011048543456039805f, 0.f);
    outv[2 * 4 + s] = (f16)fmaxf(a2 * 0.011048543456039805f, 0.f);
    outv[3 * 4 + s] = (f16)fmaxf(a3 * 0.011048543456039805f, 0.f);
  }
  f16* dst = A3 + (size_t)b * 2048 + og * 16;
  *(half8*)dst = *(half8*)&outv[0];
  *(half8*)(dst + 8) = *(half8*)&outv[8];
}

__global__ __launch_bounds__(256) void out_fused(const f16* __restrict__ P3,
                                                 const float* __restrict__ beta,
                                                 float* __restrict__ out) {
  __shared__ float red[4];
  const int b = blockIdx.x, t = threadIdx.x;
  float acc = 0.f;
#pragma unroll
  for (int oi = 0; oi < 2; ++oi) {
    int o = (oi << 8) + t;
    float v = 0.f;
#pragma unroll
    for (int kc = 0; kc < 16; ++kc) v += (float)P3[(size_t)kc * 65536 + b * 512 + o];
    acc += fmaxf(v * 0.022097086912079608f, 0.f) * beta[o];  // 1/sqrt(2048)
  }
#pragma unroll
  for (int off = 32; off > 0; off >>= 1) acc += __shfl_down(acc, off);
  if ((t & 63) == 0) red[t >> 6] = acc;
  __syncthreads();
  if (t == 0) out[b] = (red[0] + red[1] + red[2] + red[3]) * 0.044194173824159216f;
}

extern "C" void kernel_launch(void* const* d_in, const int* in_sizes, int n_in,
                              void* d_out, int out_size, void* d_ws, size_t ws_size,
                              hipStream_t stream) {
  const float* x    = (const float*)d_in[0];
  const float* w1   = (const float*)d_in[1];
  const float* w2   = (const float*)d_in[2];
  const float* w3   = (const float*)d_in[3];
  const float* beta = (const float*)d_in[4];
  float* out = (float*)d_out;

  char* wsb = (char*)d_ws;
  f16* A2 = (f16*)wsb;                                     // 8 MiB
  f16* P2 = (f16*)(wsb + (8ull << 20));                    // 8 MiB (fp16, 64 slices)
  f16* A3 = (f16*)(wsb + (16ull << 20));                   // 0.5 MiB
  f16* P3 = (f16*)(wsb + (16ull << 20) + (1ull << 19));    // 2 MiB

  l1_mfma<<<dim3(16, 4, 4), 256, 0, stream>>>(x, w1, A2);
  gemm0<<<256, 512, 0, stream>>>(A2, w2, P2);
  reduce2<<<64, 256, 0, stream>>>(P2, A3);
  gemm1<<<128, 256, 0, stream>>>(A3, w3, P3);
  out_fused<<<128, 256, 0, stream>>>(P3, beta, out);
}